// Round 3
// baseline (559.028 us; speedup 1.0000x reference)
//
#include <hip/hip_runtime.h>

#define NR   16384
#define CIN  2048
#define VDIM 128
#define SPLITK 4
#define KSL  (CIN / SPLITK)   // 512

#define FMA4(accv, s, bv) { accv.x += (s)*(bv).x; accv.y += (s)*(bv).y; accv.z += (s)*(bv).z; accv.w += (s)*(bv).w; }

// ---------------------------------------------------------------------------
// 1) Normalize columns of Fq -> V [CIN][VDIM] and Vt [VDIM][CIN]
// ---------------------------------------------------------------------------
__global__ __launch_bounds__(256) void k_normalize(const float* __restrict__ Fq,
                                                   float* __restrict__ V,
                                                   float* __restrict__ Vt) {
    int k = blockIdx.x;            // column index
    __shared__ float red[256];
    float ss = 0.f;
    for (int i = threadIdx.x; i < CIN; i += 256) {
        float v = Fq[i * VDIM + k];
        ss += v * v;
    }
    red[threadIdx.x] = ss;
    __syncthreads();
    for (int off = 128; off > 0; off >>= 1) {
        if (threadIdx.x < off) red[threadIdx.x] += red[threadIdx.x + off];
        __syncthreads();
    }
    float inv = 1.0f / sqrtf(red[0]);
    for (int i = threadIdx.x; i < CIN; i += 256) {
        float v = Fq[i * VDIM + k] * inv;
        V[i * VDIM + k] = v;
        Vt[k * CIN + i] = v;
    }
}

// ---------------------------------------------------------------------------
// 2) Gram matrix G[j][k] = v_j . v_k  (symmetric), from Vt rows (contiguous)
// ---------------------------------------------------------------------------
__global__ __launch_bounds__(64) void k_gram(const float* __restrict__ Vt,
                                             float* __restrict__ G) {
    int j = blockIdx.x, k = blockIdx.y;
    int lane = threadIdx.x;
    const float* a = Vt + j * CIN;
    const float* b = Vt + k * CIN;
    float s = 0.f;
    for (int i = lane * 4; i < CIN; i += 64 * 4) {
        float4 av = *(const float4*)(a + i);
        float4 bv = *(const float4*)(b + i);
        s += av.x * bv.x + av.y * bv.y + av.z * bv.z + av.w * bv.w;
    }
    #pragma unroll
    for (int off = 32; off > 0; off >>= 1) s += __shfl_down(s, off, 64);
    if (lane == 0) G[j * VDIM + k] = s;
}

// ---------------------------------------------------------------------------
// 3) P_y = x[:, y*512:(y+1)*512] @ V[y*512:(y+1)*512, :]   (split-K partials)
//    128x128 block tile, BK=16, 8x8 register tile, DOUBLE-BUFFERED LDS:
//    issue loads(t+1) -> compute(t) -> vmcnt-wait + LDS-write(t+1) -> 1 barrier.
// ---------------------------------------------------------------------------
__global__ __launch_bounds__(256) void k_P(const float* __restrict__ X,
                                           const float* __restrict__ V,
                                           float* __restrict__ Pp) {
    __shared__ float xs[2][16][132];   // A^T tile [k][row], pad 4
    __shared__ float vs[2][16][132];   // B tile  [k][col], pad 4
    int tid = threadIdx.x;
    int rowbase = blockIdx.x * 128;
    int kstart = blockIdx.y * KSL;
    float* P = Pp + (size_t)blockIdx.y * NR * VDIM;

    int r0 = (tid >> 4) << 2;       // 0..60
    int c0 = (tid & 15) << 2;       // 0..60
    int arow = tid >> 1;            // 0..127
    int aq   = (tid & 1) << 3;      // 0 or 8
    int brow = tid >> 5;            // 0..7   (B tile: 16 rows x 32 float4)
    int bcol = (tid & 31) << 2;     // 0..124

    float4 acc[2][2][4];
    #pragma unroll
    for (int a = 0; a < 2; ++a)
        #pragma unroll
        for (int b = 0; b < 2; ++b)
            #pragma unroll
            for (int i = 0; i < 4; ++i) acc[a][b][i] = make_float4(0.f, 0.f, 0.f, 0.f);

    const float* xsrc = X + (size_t)(rowbase + arow) * CIN + kstart + aq;

    float4 avA, avB, bvA, bvB;
    // prologue: tile 0 -> buf 0
    avA = *(const float4*)(xsrc);
    avB = *(const float4*)(xsrc + 4);
    {
        const float4* vp = (const float4*)(V + (size_t)kstart * VDIM);
        bvA = vp[tid]; bvB = vp[tid + 256];
    }
    xs[0][aq + 0][arow] = avA.x; xs[0][aq + 1][arow] = avA.y;
    xs[0][aq + 2][arow] = avA.z; xs[0][aq + 3][arow] = avA.w;
    xs[0][aq + 4][arow] = avB.x; xs[0][aq + 5][arow] = avB.y;
    xs[0][aq + 6][arow] = avB.z; xs[0][aq + 7][arow] = avB.w;
    *(float4*)&vs[0][brow][bcol]     = bvA;
    *(float4*)&vs[0][brow + 8][bcol] = bvB;
    __syncthreads();

    const int NT = KSL / 16;   // 32
    for (int t = 0; t < NT; ++t) {
        int cur = t & 1;
        if (t + 1 < NT) {      // issue next tile's global loads (in flight under compute)
            const float* xp = xsrc + (t + 1) * 16;
            avA = *(const float4*)(xp);
            avB = *(const float4*)(xp + 4);
            const float4* vp = (const float4*)(V + (size_t)(kstart + (t + 1) * 16) * VDIM);
            bvA = vp[tid]; bvB = vp[tid + 256];
        }
        #pragma unroll
        for (int kk = 0; kk < 16; ++kk) {
            float4 a0 = *(const float4*)&xs[cur][kk][r0];
            float4 a1 = *(const float4*)&xs[cur][kk][r0 + 64];
            float4 b0 = *(const float4*)&vs[cur][kk][c0];
            float4 b1 = *(const float4*)&vs[cur][kk][c0 + 64];
            float ar0[4] = {a0.x, a0.y, a0.z, a0.w};
            float ar1[4] = {a1.x, a1.y, a1.z, a1.w};
            #pragma unroll
            for (int i = 0; i < 4; ++i) {
                FMA4(acc[0][0][i], ar0[i], b0);
                FMA4(acc[0][1][i], ar0[i], b1);
                FMA4(acc[1][0][i], ar1[i], b0);
                FMA4(acc[1][1][i], ar1[i], b1);
            }
        }
        if (t + 1 == NT) break;
        int nxt = cur ^ 1;     // write staged regs -> other buffer (no barrier needed first)
        xs[nxt][aq + 0][arow] = avA.x; xs[nxt][aq + 1][arow] = avA.y;
        xs[nxt][aq + 2][arow] = avA.z; xs[nxt][aq + 3][arow] = avA.w;
        xs[nxt][aq + 4][arow] = avB.x; xs[nxt][aq + 5][arow] = avB.y;
        xs[nxt][aq + 6][arow] = avB.z; xs[nxt][aq + 7][arow] = avB.w;
        *(float4*)&vs[nxt][brow][bcol]     = bvA;
        *(float4*)&vs[nxt][brow + 8][bcol] = bvB;
        __syncthreads();
    }

    #pragma unroll
    for (int qr = 0; qr < 2; ++qr)
        #pragma unroll
        for (int i = 0; i < 4; ++i) {
            size_t row = rowbase + qr * 64 + r0 + i;
            *(float4*)(P + row * VDIM + c0)      = acc[qr][0][i];
            *(float4*)(P + row * VDIM + c0 + 64) = acc[qr][1][i];
        }
}

// ---------------------------------------------------------------------------
// 4) Row-parallel forward substitution:  s_j = 2*(p_j - sum_{k<j} s_k G[k][j])
//    p = sum of SPLITK partials. One wave handles 4 rows.
// ---------------------------------------------------------------------------
__global__ __launch_bounds__(256) void k_solve(const float* __restrict__ Pp,
                                               const float* __restrict__ G,
                                               float* __restrict__ S) {
    int lane = threadIdx.x & 63;
    int wv = threadIdx.x >> 6;
    int row0 = (blockIdx.x * 4 + wv) * 4;

    float p0[4], p1[4], s0[4], s1[4];
    #pragma unroll
    for (int r = 0; r < 4; ++r) {
        size_t base = (size_t)(row0 + r) * VDIM;
        float a0 = 0.f, a1 = 0.f;
        #pragma unroll
        for (int y = 0; y < SPLITK; ++y) {
            a0 += Pp[(size_t)y * NR * VDIM + base + lane];
            a1 += Pp[(size_t)y * NR * VDIM + base + 64 + lane];
        }
        p0[r] = a0; p1[r] = a1;
        s0[r] = 0.f; s1[r] = 0.f;
    }
    float gj0 = G[lane], gj1 = G[64 + lane];
    for (int j = 0; j < VDIM; ++j) {
        float g0 = gj0, g1 = gj1;
        if (j + 1 < VDIM) {          // prefetch next G row (off the s-chain)
            gj0 = G[(j + 1) * VDIM + lane];
            gj1 = G[(j + 1) * VDIM + 64 + lane];
        }
        float c[4];
        #pragma unroll
        for (int r = 0; r < 4; ++r) {
            float t0 = (lane < j)      ? s0[r] * g0 : 0.f;
            float t1 = (64 + lane < j) ? s1[r] * g1 : 0.f;
            c[r] = t0 + t1;
        }
        #pragma unroll
        for (int off = 1; off < 64; off <<= 1) {
            #pragma unroll
            for (int r = 0; r < 4; ++r) c[r] += __shfl_xor(c[r], off, 64);
        }
        if (j < 64) {
            if (lane == j) {
                #pragma unroll
                for (int r = 0; r < 4; ++r) s0[r] = 2.f * (p0[r] - c[r]);
            }
        } else {
            if (lane == j - 64) {
                #pragma unroll
                for (int r = 0; r < 4; ++r) s1[r] = 2.f * (p1[r] - c[r]);
            }
        }
    }
    #pragma unroll
    for (int r = 0; r < 4; ++r) {
        S[(size_t)(row0 + r) * VDIM + lane]      = s0[r];
        S[(size_t)(row0 + r) * VDIM + 64 + lane] = s1[r];
    }
}

// ---------------------------------------------------------------------------
// 5) out = x - S @ Vt + by.  128x128 tile, BK=16, double-buffered like k_P.
// ---------------------------------------------------------------------------
__global__ __launch_bounds__(256) void k_out(const float* __restrict__ X,
                                             const float* __restrict__ S,
                                             const float* __restrict__ Vt,
                                             const float* __restrict__ by,
                                             float* __restrict__ out) {
    __shared__ float st[2][16][132];   // S^T tile [k][row], pad 4
    __shared__ float vt[2][16][132];   // Vt tile  [k][col], pad 4
    int tid = threadIdx.x;
    int rb = blockIdx.y * 128;
    int cb = blockIdx.x * 128;
    int r0 = (tid >> 4) << 2;
    int c0 = (tid & 15) << 2;

    int srow = tid >> 1;            // 0..127
    int sq   = (tid & 1) << 3;      // 0 or 8
    int vk   = tid >> 4;            // 0..15
    int vm   = (tid & 15) << 3;     // 0..120

    float4 acc[2][2][4];
    #pragma unroll
    for (int a = 0; a < 2; ++a)
        #pragma unroll
        for (int b = 0; b < 2; ++b)
            #pragma unroll
            for (int i = 0; i < 4; ++i) acc[a][b][i] = make_float4(0.f, 0.f, 0.f, 0.f);

    const float* ssrc  = S  + (size_t)(rb + srow) * VDIM + sq;
    const float* vtsrc = Vt + (size_t)vk * CIN + cb + vm;

    float4 sA, sB, vA, vB;
    // prologue: tile 0 -> buf 0
    sA = *(const float4*)(ssrc);
    sB = *(const float4*)(ssrc + 4);
    vA = *(const float4*)(vtsrc);
    vB = *(const float4*)(vtsrc + 4);
    st[0][sq + 0][srow] = sA.x; st[0][sq + 1][srow] = sA.y;
    st[0][sq + 2][srow] = sA.z; st[0][sq + 3][srow] = sA.w;
    st[0][sq + 4][srow] = sB.x; st[0][sq + 5][srow] = sB.y;
    st[0][sq + 6][srow] = sB.z; st[0][sq + 7][srow] = sB.w;
    *(float4*)&vt[0][vk][vm]     = vA;
    *(float4*)&vt[0][vk][vm + 4] = vB;
    __syncthreads();

    const int NT = VDIM / 16;   // 8
    for (int t = 0; t < NT; ++t) {
        int cur = t & 1;
        if (t + 1 < NT) {
            const float* sp = ssrc + (t + 1) * 16;
            sA = *(const float4*)(sp);
            sB = *(const float4*)(sp + 4);
            const float* vp = vtsrc + (size_t)(t + 1) * 16 * CIN;
            vA = *(const float4*)(vp);
            vB = *(const float4*)(vp + 4);
        }
        #pragma unroll
        for (int kk = 0; kk < 16; ++kk) {
            float4 a0 = *(const float4*)&st[cur][kk][r0];
            float4 a1 = *(const float4*)&st[cur][kk][r0 + 64];
            float4 b0 = *(const float4*)&vt[cur][kk][c0];
            float4 b1 = *(const float4*)&vt[cur][kk][c0 + 64];
            float ar0[4] = {a0.x, a0.y, a0.z, a0.w};
            float ar1[4] = {a1.x, a1.y, a1.z, a1.w};
            #pragma unroll
            for (int i = 0; i < 4; ++i) {
                FMA4(acc[0][0][i], ar0[i], b0);
                FMA4(acc[0][1][i], ar0[i], b1);
                FMA4(acc[1][0][i], ar1[i], b0);
                FMA4(acc[1][1][i], ar1[i], b1);
            }
        }
        if (t + 1 == NT) break;
        int nxt = cur ^ 1;
        st[nxt][sq + 0][srow] = sA.x; st[nxt][sq + 1][srow] = sA.y;
        st[nxt][sq + 2][srow] = sA.z; st[nxt][sq + 3][srow] = sA.w;
        st[nxt][sq + 4][srow] = sB.x; st[nxt][sq + 5][srow] = sB.y;
        st[nxt][sq + 6][srow] = sB.z; st[nxt][sq + 7][srow] = sB.w;
        *(float4*)&vt[nxt][vk][vm]     = vA;
        *(float4*)&vt[nxt][vk][vm + 4] = vB;
        __syncthreads();
    }

    float4 by0 = *(const float4*)(by + cb + c0);
    float4 by1 = *(const float4*)(by + cb + c0 + 64);
    #pragma unroll
    for (int qr = 0; qr < 2; ++qr)
        #pragma unroll
        for (int i = 0; i < 4; ++i) {
            size_t row = rb + qr * 64 + r0 + i;
            float4 xv0 = *(const float4*)(X + row * CIN + cb + c0);
            float4 xv1 = *(const float4*)(X + row * CIN + cb + c0 + 64);
            float4 o0, o1;
            o0.x = xv0.x - acc[qr][0][i].x + by0.x;
            o0.y = xv0.y - acc[qr][0][i].y + by0.y;
            o0.z = xv0.z - acc[qr][0][i].z + by0.z;
            o0.w = xv0.w - acc[qr][0][i].w + by0.w;
            o1.x = xv1.x - acc[qr][1][i].x + by1.x;
            o1.y = xv1.y - acc[qr][1][i].y + by1.y;
            o1.z = xv1.z - acc[qr][1][i].z + by1.z;
            o1.w = xv1.w - acc[qr][1][i].w + by1.w;
            *(float4*)(out + row * CIN + cb + c0)      = o0;
            *(float4*)(out + row * CIN + cb + c0 + 64) = o1;
        }
}

// ---------------------------------------------------------------------------
extern "C" void kernel_launch(void* const* d_in, const int* in_sizes, int n_in,
                              void* d_out, int out_size, void* d_ws, size_t ws_size,
                              hipStream_t stream) {
    const float* x  = (const float*)d_in[0];   // [16384][2048]
    const float* Fq = (const float*)d_in[1];   // [2048][128]
    const float* by = (const float*)d_in[2];   // [2048]
    float* out = (float*)d_out;
    float* ws = (float*)d_ws;

    float* V  = ws;                    // 2048*128            = 262144
    float* Vt = ws + 262144;           // 128*2048            = 262144
    float* G  = ws + 524288;           // 128*128             = 16384
    float* S  = ws + 540672;           // 16384*128           = 2097152
    // Split-K partials of P live in d_out (4 x 8 MB << 134 MB), consumed by
    // k_solve before k_out overwrites d_out with the final result.
    float* Pp = out;

    k_normalize<<<VDIM, 256, 0, stream>>>(Fq, V, Vt);
    k_gram<<<dim3(VDIM, VDIM), 64, 0, stream>>>(Vt, G);
    k_P<<<dim3(NR / 128, SPLITK), 256, 0, stream>>>(x, V, Pp);
    k_solve<<<NR / 16, 256, 0, stream>>>(Pp, G, S);
    k_out<<<dim3(CIN / 128, NR / 128), 256, 0, stream>>>(x, S, Vt, by, out);
}